// Round 12
// baseline (148.832 us; speedup 1.0000x reference)
//
#include <hip/hip_runtime.h>
#include <hip/hip_bf16.h>

#define D_IN  768
#define D_E   256
#define M_TOT 512      // B*S
#define E_TOT 100000

typedef __attribute__((ext_vector_type(4))) float f32x4;
typedef __attribute__((ext_vector_type(8))) short bf16x8;

__device__ __forceinline__ unsigned short bf16bits(float f) {
    union { __hip_bfloat16 h; unsigned short u; } c;
    c.h = __float2bfloat16(f);
    return c.u;
}

__device__ __forceinline__ void gload_lds16(const void* g, void* l) {
    __builtin_amdgcn_global_load_lds(
        (const __attribute__((address_space(1))) void*)g,
        (__attribute__((address_space(3))) void*)l, 16, 0, 0);
}

// ---------------------------------------------------------------------------
// Fused prep+proj (unchanged — at BW floor):
//   blocks [0,64):    proj  qb[m][e] = bf16(tanh(x@W^T+b)/||row||)
//   blocks [64,1627): prep  eb[n][k] = bf16(en[n][k]/||en[n]||)
// ---------------------------------------------------------------------------
#define PROJ_BLOCKS 64
#define PREP_BLOCKS 1563
#define PP_GRID (PROJ_BLOCKS + PREP_BLOCKS)
#define PTM 8
#define PBK 64
#define PROUNDS (D_IN / PBK)             // 12

__global__ __launch_bounds__(512) void fused_pp(
    const float* __restrict__ x, const float* __restrict__ W,
    const float* __restrict__ b, const float* __restrict__ en,
    unsigned short* __restrict__ qb, unsigned short* __restrict__ eb)
{
    __shared__ float ws[D_E * (PBK + 1)];
    __shared__ float xs[PTM][PBK];
    __shared__ float red[PTM][4];
    __shared__ float qiv[PTM];

    const int t   = threadIdx.x;
    const int bid = blockIdx.x;

    if (bid >= PROJ_BLOCKS) {
        const int lane = t & 63;
        const int gw   = (bid - PROJ_BLOCKS) * 8 + (t >> 6);
        #pragma unroll 2
        for (int i = 0; i < 8; ++i) {
            const int row = gw * 8 + i;
            if (row >= E_TOT) break;
            const float4 v = *reinterpret_cast<const float4*>(
                en + (size_t)row * D_E + lane * 4);
            float s = v.x*v.x + v.y*v.y + v.z*v.z + v.w*v.w;
            #pragma unroll
            for (int off = 1; off < 64; off <<= 1) s += __shfl_xor(s, off, 64);
            const float sc = 1.0f / fmaxf(sqrtf(s), 1e-8f);
            union { unsigned short u[4]; uint2 d; } o;
            o.u[0] = bf16bits(v.x * sc); o.u[1] = bf16bits(v.y * sc);
            o.u[2] = bf16bits(v.z * sc); o.u[3] = bf16bits(v.w * sc);
            *reinterpret_cast<uint2*>(eb + (size_t)row * D_E + lane * 4) = o.d;
        }
        return;
    }

    const int m0   = bid * PTM;
    const int e    = t & 255;
    const int half = t >> 8;
    const int c4   = t & 15;
    const int rr   = t >> 4;

    float4 wreg[8];
    float  xreg = 0.f;
    float  acc[4] = {0.f, 0.f, 0.f, 0.f};

    #pragma unroll
    for (int i = 0; i < 8; ++i)
        wreg[i] = *reinterpret_cast<const float4*>(
            &W[(size_t)(i * 32 + rr) * D_IN + c4 * 4]);
    xreg = x[(size_t)(m0 + (t >> 6)) * D_IN + (t & 63)];

    for (int rd = 0; rd < PROUNDS; ++rd) {
        #pragma unroll
        for (int i = 0; i < 8; ++i) {
            float* dst = &ws[(i * 32 + rr) * (PBK + 1) + c4 * 4];
            dst[0] = wreg[i].x; dst[1] = wreg[i].y;
            dst[2] = wreg[i].z; dst[3] = wreg[i].w;
        }
        xs[t >> 6][t & 63] = xreg;
        __syncthreads();
        if (rd + 1 < PROUNDS) {
            const int k0 = (rd + 1) * PBK;
            #pragma unroll
            for (int i = 0; i < 8; ++i)
                wreg[i] = *reinterpret_cast<const float4*>(
                    &W[(size_t)(i * 32 + rr) * D_IN + k0 + c4 * 4]);
            xreg = x[(size_t)(m0 + (t >> 6)) * D_IN + k0 + (t & 63)];
        }
        #pragma unroll
        for (int k = 0; k < PBK; ++k) {
            const float wv = ws[e * (PBK + 1) + k];
            #pragma unroll
            for (int j = 0; j < 4; ++j)
                acc[j] = fmaf(xs[half * 4 + j][k], wv, acc[j]);
        }
        __syncthreads();
    }

    const float bias = b[e];
    const int wv4 = (t >> 6) & 3;
    const int lane = t & 63;
    float q[4];
    #pragma unroll
    for (int j = 0; j < 4; ++j) {
        q[j] = tanhf(acc[j] + bias);
        float s = q[j] * q[j];
        #pragma unroll
        for (int off = 1; off < 64; off <<= 1) s += __shfl_xor(s, off, 64);
        if (lane == 0) red[half * 4 + j][wv4] = s;
    }
    __syncthreads();
    if (t < PTM) {
        const float s = red[t][0] + red[t][1] + red[t][2] + red[t][3];
        qiv[t] = 1.0f / fmaxf(sqrtf(s), 1e-8f);
    }
    __syncthreads();
    #pragma unroll
    for (int j = 0; j < 4; ++j)
        qb[(size_t)(m0 + half * 4 + j) * D_E + e] =
            bf16bits(q[j] * qiv[half * 4 + j]);
}

// ---------------------------------------------------------------------------
// Kernel 2 (v12): DRAM-write-locality design.
// Block = 32m x 512n (one super-tile, full K=256), 8 waves; wave = 32m x 64n
// with a PRIVATE per-wave pipeline: its own 64n x 64k dbuf pieces (8 KB each)
// staged via global_load_lds + per-wave counted vmcnt — ZERO barriers in the
// k-loop. q (32x256) via LDS -> 16 reg frags. Epilogue: acc -> 64 KB LDS
// transpose (swizzled, conflict-free), then each wave-store writes 1 KB
// CONTIGUOUS of one row; each row gets its full 2 KB back-to-back -> DRAM
// pages see dense 2 KB runs instead of 64-256B scatter.
// LDS pool 128 KB: es[8 waves][2][8 KB] during compute; reused for q stage
// (16 KB) in the prologue and the 64 KB transpose buffer in the epilogue.
// ---------------------------------------------------------------------------
#define SBM 32
#define SBN 512
#define NGN 196                         // 196*512 = 100352 >= 100000
#define SIM_GRID (16 * NGN)             // 3136 (%8 == 0)

__device__ __forceinline__ void stage_piece(
    const unsigned short* __restrict__ eb, int nw, int kk,
    unsigned short* dst, int lane)
{
    #pragma unroll
    for (int i = 0; i < 8; ++i) {
        const int c  = i * 64 + lane;     // 16B-chunk index in piece
        const int n  = c >> 3;            // 0..63 entity row
        const int c8 = c & 7;             // chunk within 128B row
        int rg = nw + n;
        if (rg >= E_TOT) rg = E_TOT - 1;  // clamp: always 8 uniform ops
        gload_lds16(eb + (size_t)rg * D_E + kk * 64 + ((c8 ^ (n & 7)) << 3),
                    (void*)&dst[c * 8]);
    }
}

__global__ __launch_bounds__(512, 2) void sim_kernel(
    const unsigned short* __restrict__ eb, const unsigned short* __restrict__ qb,
    float* __restrict__ out)
{
    __shared__ unsigned short pool[65536];   // 128 KB, multi-purpose

    const int t    = threadIdx.x;
    const int lane = t & 63;
    const int w    = t >> 6;        // 0..7
    const int l15  = lane & 15;
    const int lk   = lane >> 4;     // 0..3

    // chunked bijective XCD swizzle: the 16 m-blocks of one n-group are
    // virtually consecutive -> same XCD -> shared eb slice in L2 AND a
    // combined dense write footprint.
    const int vbid = (blockIdx.x & 7) * (SIM_GRID / 8) + (blockIdx.x >> 3);
    const int mg = vbid & 15;       // 0..15
    const int ng = vbid >> 4;       // 0..195
    const int m0 = mg * SBM;
    const int n0 = ng * SBN;
    const int nw = n0 + w * 64;     // this wave's entity base

    char* poolb = reinterpret_cast<char*>(pool);

    // ---- prologue: q tile (32x256) via pool[0:16K) ----
    #pragma unroll
    for (int i = 0; i < 2; ++i) {
        const int c   = i * 512 + t;        // 0..1023
        const int row = c >> 5;             // 0..31
        const int c16 = c & 31;
        gload_lds16(qb + (size_t)(m0 + row) * D_E + ((c16 ^ (row & 7)) << 3),
                    (void*)&pool[c * 8]);
    }
    asm volatile("s_waitcnt vmcnt(0)" ::: "memory");
    __builtin_amdgcn_sched_barrier(0);
    __builtin_amdgcn_s_barrier();

    bf16x8 qf[2][8];
    #pragma unroll
    for (int mf = 0; mf < 2; ++mf) {
        const int rq = mf * 16 + l15;
        #pragma unroll
        for (int ks = 0; ks < 8; ++ks) {
            const int cb = (ks * 64 + lk * 16) ^ ((l15 & 7) << 4);
            qf[mf][ks] = *reinterpret_cast<const bf16x8*>(poolb + rq * 512 + cb);
        }
    }
    asm volatile("s_waitcnt lgkmcnt(0)" ::: "memory");
    __builtin_amdgcn_sched_barrier(0);
    __builtin_amdgcn_s_barrier();           // q region now free for es

    // ---- per-wave es dbuf: pool + w*16KB, two 8 KB pieces ----
    unsigned short* es0 = pool + w * 8192;          // ushort index
    unsigned short* es1 = pool + w * 8192 + 4096;
    const char* esb0 = reinterpret_cast<const char*>(es0);
    const char* esb1 = reinterpret_cast<const char*>(es1);

    stage_piece(eb, nw, 0, es0, lane);
    stage_piece(eb, nw, 1, es1, lane);

    f32x4 acc[2][4];
    #pragma unroll
    for (int mf = 0; mf < 2; ++mf)
        #pragma unroll
        for (int nf = 0; nf < 4; ++nf)
            acc[mf][nf] = (f32x4){0.f, 0.f, 0.f, 0.f};

    #pragma unroll
    for (int kk = 0; kk < 4; ++kk) {
        // wait: piece kk staged (per-wave). In flight at entry: piece kk (8)
        // + piece kk+1 (8)  ->  vmcnt(8) retires kk; last iter: vmcnt(0).
        if (kk < 3) asm volatile("s_waitcnt vmcnt(8)" ::: "memory");
        else        asm volatile("s_waitcnt vmcnt(0)" ::: "memory");
        __builtin_amdgcn_sched_barrier(0);

        const char* esb = (kk & 1) ? esb1 : esb0;
        #pragma unroll
        for (int s = 0; s < 2; ++s) {
            const int ks = kk * 2 + s;
            bf16x8 ef[4];
            #pragma unroll
            for (int nf = 0; nf < 4; ++nf) {
                const int n = nf * 16 + l15;
                const int cb = (s * 64 + lk * 16) ^ ((n & 7) << 4);
                ef[nf] = *reinterpret_cast<const bf16x8*>(esb + n * 128 + cb);
            }
            #pragma unroll
            for (int mf = 0; mf < 2; ++mf)
                #pragma unroll
                for (int nf = 0; nf < 4; ++nf)
                    acc[mf][nf] = __builtin_amdgcn_mfma_f32_16x16x32_bf16(
                        ef[nf], qf[mf][ks], acc[mf][nf], 0, 0, 0);
        }
        __builtin_amdgcn_sched_barrier(0);
        // stage piece kk+2 into the buffer just freed (reads already in regs)
        if (kk == 0) stage_piece(eb, nw, 2, es0, lane);
        if (kk == 1) stage_piece(eb, nw, 3, es1, lane);
    }

    // ---- epilogue: transpose via pool[0:64K) then 1KB-contiguous stores ----
    __builtin_amdgcn_s_barrier();           // all waves done with es

    // write acc -> tbuf[32 rows][512 floats], 16B-chunk XOR swizzle by row
    #pragma unroll
    for (int mf = 0; mf < 2; ++mf) {
        const int mrow = mf * 16 + l15;
        #pragma unroll
        for (int nf = 0; nf < 4; ++nf) {
            const int cc = w * 16 + nf * 4 + lk;      // 16B chunk (0..127)
            *reinterpret_cast<f32x4*>(
                poolb + mrow * 2048 + ((cc ^ (mrow & 7)) << 4)) = acc[mf][nf];
        }
    }
    asm volatile("s_waitcnt lgkmcnt(0)" ::: "memory");
    __builtin_amdgcn_sched_barrier(0);
    __builtin_amdgcn_s_barrier();

    // linear stores: per wave-instr 64 lanes read 64 consecutive chunks of
    // ONE row (1 KB) and store them contiguously; each row leaves as 2 KB.
    #pragma unroll
    for (int j = 0; j < 8; ++j) {
        const int c    = j * 512 + t;       // 0..4095 (32 rows x 128 chunks)
        const int rrow = c >> 7;
        const int cc   = c & 127;
        const f32x4 v = *reinterpret_cast<const f32x4*>(
            poolb + rrow * 2048 + ((cc ^ (rrow & 7)) << 4));
        const int n = n0 + cc * 4;
        if (n < E_TOT)                       // E%4==0 -> whole f32x4 valid
            *reinterpret_cast<f32x4*>(
                &out[(size_t)(m0 + rrow) * E_TOT + n]) = v;
    }
}

// ---------------------------------------------------------------------------
extern "C" void kernel_launch(void* const* d_in, const int* in_sizes, int n_in,
                              void* d_out, int out_size, void* d_ws, size_t ws_size,
                              hipStream_t stream) {
    const float* x  = (const float*)d_in[0];   // [4,128,768]
    const float* W  = (const float*)d_in[1];   // [256,768]
    const float* b  = (const float*)d_in[2];   // [256]
    const float* en = (const float*)d_in[3];   // [100000,256]
    float* out = (float*)d_out;                // [512,100000]

    unsigned short* qb = (unsigned short*)d_ws;                 // 256 KB
    unsigned short* eb = (unsigned short*)((char*)d_ws + (size_t)M_TOT * D_E * 2);

    fused_pp<<<PP_GRID, 512, 0, stream>>>(x, W, b, en, qb, eb); // 1627 blocks
    sim_kernel<<<SIM_GRID, 512, 0, stream>>>(eb, qb, out);      // 3136 blocks
}